// Round 5
// baseline (27530.807 us; speedup 1.0000x reference)
//
#include <hip/hip_runtime.h>
#include <hip/hip_fp16.h>

#define T_LEN 65536
#define FDIM  128
#define NGATE 512   // 4*F for layer-2 LSTM

typedef int iv4 __attribute__((ext_vector_type(4)));

// ---------- fast math helpers ----------
__device__ __forceinline__ float frcp(float x) { return __builtin_amdgcn_rcpf(x); }
#define LOG2E 1.4426950408889634f
__device__ __forceinline__ float sigmoid_f(float x) {
  return frcp(1.f + __builtin_amdgcn_exp2f(-LOG2E * x));
}

// ---------- DPP cross-lane reduce (Phase A/C only) ----------
template<int CTRL, int ROWM, int BANKM, bool BC>
__device__ __forceinline__ float dpp_mov0(float x) {
  return __int_as_float(
      __builtin_amdgcn_update_dpp(0, __float_as_int(x), CTRL, ROWM, BANKM, BC));
}
__device__ __forceinline__ float red8(float a) {
  a += dpp_mov0<0xB1, 0xF, 0xF, true>(a);   // quad_perm xor-1
  a += dpp_mov0<0x4E, 0xF, 0xF, true>(a);   // quad_perm xor-2
  a += dpp_mov0<0x114, 0xF, 0xA, true>(a);  // row_shr:4, banks 1&3
  return a;
}
__device__ __forceinline__ float red16(float a) {
  a += dpp_mov0<0x111, 0xF, 0xF, true>(a);
  a += dpp_mov0<0x112, 0xF, 0xF, true>(a);
  a += dpp_mov0<0x114, 0xF, 0xF, true>(a);
  a += dpp_mov0<0x118, 0xF, 0xF, true>(a);
  return a;
}

union H8 { uint4 u; __half h[8]; };

// barrier draining ONLY lgkm (LDS): no per-step vmcnt round-trip.
#define LDS_BARRIER() asm volatile("s_waitcnt lgkmcnt(0)\n\ts_barrier" ::: "memory")

// ---------------------------------------------------------------------------
// Phase A: per-unit gate precompute, stored as [T][128] x {i,f,g,o} f16 quads.
// ---------------------------------------------------------------------------
__global__ __launch_bounds__(512, 2)
void gx_kernel(const float* __restrict__ x, const float* __restrict__ Wih2,
               const float* __restrict__ bih2, const float* __restrict__ bhh2,
               __half* __restrict__ gx)
{
  __shared__ float xs[64 * FDIM];           // 32 KB tile of x
  const int tid  = threadIdx.x;
  const int lane = tid & 63;
  const int wave = tid >> 6;
  const int q    = lane & 7;
  const int pl   = lane >> 3;
  const int p    = wave * 8 + pl;
  const int u0   = 2 * p;

  float w[8][16];
  float bias[8];
#pragma unroll
  for (int j = 0; j < 8; ++j) {
    const int row = ((j >> 1) * 128) + u0 + (j & 1);   // j = {i0,i1,f0,f1,g0,g1,o0,o1}
    const int base = row * FDIM + q * 16;
#pragma unroll
    for (int k = 0; k < 16; ++k) w[j][k] = Wih2[base + k];
    bias[j] = bih2[row] + bhh2[row];
  }

  const int t0 = blockIdx.x * 64;
  const float4* xg = (const float4*)(x + (size_t)t0 * FDIM);
  float4* xs4 = (float4*)xs;
#pragma unroll
  for (int i = 0; i < 4; ++i) xs4[tid + i * 512] = xg[tid + i * 512];
  __syncthreads();

  for (int tt = 0; tt < 64; ++tt) {
    float hv[16];
    const float4* hv4 = (const float4*)(xs + tt * FDIM + q * 16);
    *(float4*)&hv[0]  = hv4[0];
    *(float4*)&hv[4]  = hv4[1];
    *(float4*)&hv[8]  = hv4[2];
    *(float4*)&hv[12] = hv4[3];

    float acc[8];
#pragma unroll
    for (int j = 0; j < 8; ++j) {
      float a = 0.f;
#pragma unroll
      for (int k = 0; k < 16; ++k) a = fmaf(w[j][k], hv[k], a);
      acc[j] = red8(a) + bias[j];
    }
    if (q == 4) {
      // store unit-major gate quads: unit u0 -> {i0,f0,g0,o0}, u0+1 -> {i1,f1,g1,o1}
      H8 pk;
      pk.h[0] = __float2half(acc[0]); pk.h[1] = __float2half(acc[2]);
      pk.h[2] = __float2half(acc[4]); pk.h[3] = __float2half(acc[6]);
      pk.h[4] = __float2half(acc[1]); pk.h[5] = __float2half(acc[3]);
      pk.h[6] = __float2half(acc[5]); pk.h[7] = __float2half(acc[7]);
      *((uint4*)(gx + ((size_t)(t0 + tt) * FDIM + u0) * 4)) = pk.u;
    }
  }
}

// ---------------------------------------------------------------------------
// Phase B: sequential LSTM-2 scan, pure int8 VALU dot4. One block, 512
// threads, 8 waves (2/SIMD). lane = (gate g = lane>>4, unit u = 16*wave +
// (lane&15)); each lane owns the FULL W_hh2 row (128 int8 in 32 VGPRs,
// per-row scale, exact int32 accumulate) -> no cross-lane reduction, no MFMA
// broadcast waste. h (int8) broadcast from LDS via 8x ds_read_b128.
// Each lane activates its own gate (1 transcendental pair), exchanges the
// unit's {i,f,g,o} quad through same-wave LDS (no barrier), then all 4
// g-copies redundantly update c and compute h (tanh(c) = pair #2).
// One lgkm-only s_barrier per step publishes the quantized h.
// ---------------------------------------------------------------------------
__global__ __launch_bounds__(512)
void scan_kernel(const __half* __restrict__ gx, const float* __restrict__ Whh2,
                 const float* __restrict__ h20, const float* __restrict__ c20,
                 float* __restrict__ hist)
{
  __shared__ __align__(16) signed char hq[2][FDIM];   // int8 h, double-buffered
  __shared__ __align__(16) float actb[8][64];         // per-wave act exchange

  const int tid  = threadIdx.x;
  const int lane = tid & 63;
  const int wave = tid >> 6;        // 0..7
  const int ul   = lane & 15;
  const int g    = lane >> 4;       // 0..3 = {i,f,g,o}
  const int u    = 16 * wave + ul;  // 0..127
  const int row  = g * FDIM + u;    // unique W_hh2 row per lane (512 total)

  // ---- init: quantize own W_hh2 row to int8 with per-row scale ----
  const float* wr = Whh2 + (size_t)row * FDIM;
  float m = 1e-20f;
#pragma unroll
  for (int k = 0; k < FDIM; k += 4) {
    const float4 v = *(const float4*)(wr + k);
    m = fmaxf(m, fmaxf(fmaxf(fabsf(v.x), fabsf(v.y)),
                       fmaxf(fabsf(v.z), fabsf(v.w))));
  }
  const float inv = 127.f / m;
  const float dq  = m * (1.f / 16129.f);    // m/127 * 1/127
  int wq[32];
#pragma unroll
  for (int d = 0; d < 32; ++d) {
    const float4 v = *(const float4*)(wr + 4 * d);
    int b0 = (int)rintf(v.x * inv), b1 = (int)rintf(v.y * inv);
    int b2 = (int)rintf(v.z * inv), b3 = (int)rintf(v.w * inv);
    b0 = b0 < -127 ? -127 : (b0 > 127 ? 127 : b0);
    b1 = b1 < -127 ? -127 : (b1 > 127 ? 127 : b1);
    b2 = b2 < -127 ? -127 : (b2 > 127 ? 127 : b2);
    b3 = b3 < -127 ? -127 : (b3 > 127 ? 127 : b3);
    wq[d] = (b0 & 255) | ((b1 & 255) << 8) | ((b2 & 255) << 16) | ((b3 & 255) << 24);
  }

  // lane-constant activation selectors: gate 2 uses tanh = 2*sigmoid(2x)-1
  const bool isg  = (g == 2);
  const float selm = isg ? 2.f : 1.f;
  const float selA = isg ? 2.f : 1.f;
  const float selB = isg ? -1.f : 0.f;

  float c = c20[u];                 // redundant across the 4 g-copies
  if (tid < FDIM) {
    const float hv = fminf(fmaxf(h20[tid], -1.f), 1.f);
    hq[0][tid] = (signed char)(int)rintf(127.f * hv);
  }

  const char* gxb = (const char*)gx;        // step stride: 128 units * 8 B
  const int goff  = u * 8 + g * 2;          // this lane's gate value (f16)
  unsigned short gpf[8];
#pragma unroll
  for (int s = 0; s < 8; ++s)
    gpf[s] = *(const unsigned short*)(gxb + (size_t)s * 1024 + goff);

  float* actw = actb[wave];
  __syncthreads();

  for (int t = 0; t < T_LEN; t += 8) {
#pragma unroll
    for (int s = 0; s < 8; ++s) {
      const int tt = t + s;
      const signed char* hrow = hq[tt & 1];

      // 32x sdot4 in 4 independent chains; h broadcast (same addr all lanes)
      int acc0 = 0, acc1 = 0, acc2 = 0, acc3 = 0;
#pragma unroll
      for (int r = 0; r < 8; ++r) {
        const iv4 hv = *(const iv4*)(hrow + 16 * r);
        acc0 = __builtin_amdgcn_sdot4(wq[4 * r + 0], hv.x, acc0, false);
        acc1 = __builtin_amdgcn_sdot4(wq[4 * r + 1], hv.y, acc1, false);
        acc2 = __builtin_amdgcn_sdot4(wq[4 * r + 2], hv.z, acc2, false);
        acc3 = __builtin_amdgcn_sdot4(wq[4 * r + 3], hv.w, acc3, false);
      }
      const int iacc = (acc0 + acc1) + (acc2 + acc3);

      __half_raw hrw; hrw.x = gpf[s];
      const float gxf = __half2float(*(__half*)&hrw);
      gpf[s] = *(const unsigned short*)(
          gxb + (size_t)((tt + 8) & (T_LEN - 1)) * 1024 + goff);

      // pre-activation and this lane's gate activation (1 exp2 + 1 rcp)
      const float pre = fmaf((float)iacc, dq, gxf);
      const float e   = __builtin_amdgcn_exp2f(-LOG2E * (pre * selm));
      const float act = fmaf(frcp(1.f + e), selA, selB);

      // same-wave quad exchange: {i,f,g,o} for unit u (no barrier needed)
      actw[ul * 4 + g] = act;
      asm volatile("s_waitcnt lgkmcnt(0)" ::: "memory");
      const float4 qd = *(const float4*)(actw + ul * 4);

      // c update + h (redundant across 4 g-copies; pair #2: tanh(c))
      c = fmaf(qd.y, c, qd.x * qd.z);
      const float tc = fmaf(frcp(1.f + __builtin_amdgcn_exp2f(-2.f * LOG2E * c)),
                            2.f, -1.f);
      const float h = qd.w * tc;

      if (g == 0) {
        hq[(tt + 1) & 1][u] = (signed char)(int)rintf(127.f * h);
        hist[(size_t)tt * FDIM + u] = h;     // fire-and-forget
      }
      LDS_BARRIER();
    }
  }
}

// ---------------------------------------------------------------------------
// Phase C: out[t] = 2*sigmoid(W_fc @ h2[t] + b_fc), in place on d_out.
// ---------------------------------------------------------------------------
__global__ __launch_bounds__(512, 2)
void fc_kernel(const float* __restrict__ Wfc, const float* __restrict__ bfc,
               float* __restrict__ io)
{
  __shared__ float hs[64 * FDIM];
  const int tid  = threadIdx.x;
  const int lane = tid & 63;
  const int wave = tid >> 6;
  const int q    = lane & 15;
  const int gl   = lane >> 4;
  const int g    = wave * 4 + gl;           // 0..31

  float w[4][8];
#pragma unroll
  for (int r = 0; r < 4; ++r)
#pragma unroll
    for (int k = 0; k < 8; ++k)
      w[r][k] = Wfc[(4 * g + r) * FDIM + q * 8 + k];
  const float4 bias = ((const float4*)bfc)[g];

  const int t0 = blockIdx.x * 64;
  float4* iog = (float4*)(io + (size_t)t0 * FDIM);
  float4* hs4 = (float4*)hs;
#pragma unroll
  for (int i = 0; i < 4; ++i) hs4[tid + i * 512] = iog[tid + i * 512];
  __syncthreads();          // all reads of this block's rows done before writes

  for (int tt = 0; tt < 64; ++tt) {
    float hv[8];
    const float4* hv4 = (const float4*)(hs + tt * FDIM + q * 8);
    *(float4*)&hv[0] = hv4[0];
    *(float4*)&hv[4] = hv4[1];
    float acc[4];
#pragma unroll
    for (int r = 0; r < 4; ++r) {
      float a = 0.f;
#pragma unroll
      for (int k = 0; k < 8; ++k) a = fmaf(w[r][k], hv[k], a);
      acc[r] = red16(a);
    }
    if (q == 15) {
      float4 o;
      o.x = 2.f * sigmoid_f(acc[0] + bias.x);
      o.y = 2.f * sigmoid_f(acc[1] + bias.y);
      o.z = 2.f * sigmoid_f(acc[2] + bias.z);
      o.w = 2.f * sigmoid_f(acc[3] + bias.w);
      *(float4*)(io + (size_t)(t0 + tt) * FDIM + 4 * g) = o;
    }
  }
}

// ---------------------------------------------------------------------------
extern "C" void kernel_launch(void* const* d_in, const int* in_sizes, int n_in,
                              void* d_out, int out_size, void* d_ws, size_t ws_size,
                              hipStream_t stream) {
  const float* x    = (const float*)d_in[0];
  // d_in[1..2]: h1_0/c1_0  -- layer-1 LSTM never affects the output: skipped.
  const float* h20  = (const float*)d_in[3];
  const float* c20  = (const float*)d_in[4];
  // d_in[5..8]: W_ih1/W_hh1/b_ih1/b_hh1 -- dead.
  const float* Wih2 = (const float*)d_in[9];
  const float* Whh2 = (const float*)d_in[10];
  const float* bih2 = (const float*)d_in[11];
  const float* bhh2 = (const float*)d_in[12];
  const float* Wfc  = (const float*)d_in[13];
  const float* bfc  = (const float*)d_in[14];

  float*  out = (float*)d_out;              // [T,128]: h2 history, then final out
  __half* gx  = (__half*)d_ws;              // [T][128][4] f16 gate quads (67 MB)

  gx_kernel<<<T_LEN / 64, 512, 0, stream>>>(x, Wih2, bih2, bhh2, gx);
  scan_kernel<<<1, 512, 0, stream>>>(gx, Whh2, h20, c20, out);
  fc_kernel<<<T_LEN / 64, 512, 0, stream>>>(Wfc, bfc, out);
}

// Round 6
// 23633.833 us; speedup vs baseline: 1.1649x; 1.1649x over previous
//
#include <hip/hip_runtime.h>
#include <hip/hip_fp16.h>

#define T_LEN 65536
#define FDIM  128
#define NGATE 512   // 4*F for layer-2 LSTM

typedef int iv4 __attribute__((ext_vector_type(4)));

// ---------- fast math helpers ----------
__device__ __forceinline__ float frcp(float x) { return __builtin_amdgcn_rcpf(x); }
#define LOG2E 1.4426950408889634f
__device__ __forceinline__ float sigmoid_f(float x) {
  return frcp(1.f + __builtin_amdgcn_exp2f(-LOG2E * x));
}

// ---------- DPP cross-lane ops ----------
template<int CTRL, int ROWM, int BANKM, bool BC>
__device__ __forceinline__ float dpp_mov0(float x) {
  return __int_as_float(
      __builtin_amdgcn_update_dpp(0, __float_as_int(x), CTRL, ROWM, BANKM, BC));
}
// quad_perm broadcast of quad-lane Q to all 4 lanes of the quad
template<int Q>
__device__ __forceinline__ float qbcast(float x) {
  return dpp_mov0<(Q | (Q << 2) | (Q << 4) | (Q << 6)), 0xF, 0xF, true>(x);
}
__device__ __forceinline__ float red8(float a) {
  a += dpp_mov0<0xB1, 0xF, 0xF, true>(a);   // quad_perm xor-1
  a += dpp_mov0<0x4E, 0xF, 0xF, true>(a);   // quad_perm xor-2
  a += dpp_mov0<0x114, 0xF, 0xA, true>(a);  // row_shr:4, banks 1&3
  return a;
}
__device__ __forceinline__ float red16(float a) {
  a += dpp_mov0<0x111, 0xF, 0xF, true>(a);
  a += dpp_mov0<0x112, 0xF, 0xF, true>(a);
  a += dpp_mov0<0x114, 0xF, 0xF, true>(a);
  a += dpp_mov0<0x118, 0xF, 0xF, true>(a);
  return a;
}

union H8 { uint4 u; __half h[8]; };

// barrier draining ONLY lgkm (LDS): no per-step vmcnt round-trip.
#define LDS_BARRIER() asm volatile("s_waitcnt lgkmcnt(0)\n\ts_barrier" ::: "memory")

// ---------------------------------------------------------------------------
// Phase A: per-unit gate precompute, stored as [T][128] x {i,f,g,o} f16 quads.
// ---------------------------------------------------------------------------
__global__ __launch_bounds__(512, 2)
void gx_kernel(const float* __restrict__ x, const float* __restrict__ Wih2,
               const float* __restrict__ bih2, const float* __restrict__ bhh2,
               __half* __restrict__ gx)
{
  __shared__ float xs[64 * FDIM];           // 32 KB tile of x
  const int tid  = threadIdx.x;
  const int lane = tid & 63;
  const int wave = tid >> 6;
  const int q    = lane & 7;
  const int pl   = lane >> 3;
  const int p    = wave * 8 + pl;
  const int u0   = 2 * p;

  float w[8][16];
  float bias[8];
#pragma unroll
  for (int j = 0; j < 8; ++j) {
    const int row = ((j >> 1) * 128) + u0 + (j & 1);   // j = {i0,i1,f0,f1,g0,g1,o0,o1}
    const int base = row * FDIM + q * 16;
#pragma unroll
    for (int k = 0; k < 16; ++k) w[j][k] = Wih2[base + k];
    bias[j] = bih2[row] + bhh2[row];
  }

  const int t0 = blockIdx.x * 64;
  const float4* xg = (const float4*)(x + (size_t)t0 * FDIM);
  float4* xs4 = (float4*)xs;
#pragma unroll
  for (int i = 0; i < 4; ++i) xs4[tid + i * 512] = xg[tid + i * 512];
  __syncthreads();

  for (int tt = 0; tt < 64; ++tt) {
    float hv[16];
    const float4* hv4 = (const float4*)(xs + tt * FDIM + q * 16);
    *(float4*)&hv[0]  = hv4[0];
    *(float4*)&hv[4]  = hv4[1];
    *(float4*)&hv[8]  = hv4[2];
    *(float4*)&hv[12] = hv4[3];

    float acc[8];
#pragma unroll
    for (int j = 0; j < 8; ++j) {
      float a = 0.f;
#pragma unroll
      for (int k = 0; k < 16; ++k) a = fmaf(w[j][k], hv[k], a);
      acc[j] = red8(a) + bias[j];
    }
    if (q == 4) {
      // store unit-major gate quads: unit u0 -> {i0,f0,g0,o0}, u0+1 -> {i1,f1,g1,o1}
      H8 pk;
      pk.h[0] = __float2half(acc[0]); pk.h[1] = __float2half(acc[2]);
      pk.h[2] = __float2half(acc[4]); pk.h[3] = __float2half(acc[6]);
      pk.h[4] = __float2half(acc[1]); pk.h[5] = __float2half(acc[3]);
      pk.h[6] = __float2half(acc[5]); pk.h[7] = __float2half(acc[7]);
      *((uint4*)(gx + ((size_t)(t0 + tt) * FDIM + u0) * 4)) = pk.u;
    }
  }
}

// ---------------------------------------------------------------------------
// Phase B: sequential LSTM-2 scan, int8 VALU sdot4 + quad-DPP gate exchange.
// One block, 512 threads, 8 waves (2/SIMD).
//   lane = 4*ul + g:  quad = one unit u = 16*wave + ul,  g in {i,f,g,o}.
// Each lane owns the FULL W_hh2 row (128 int8 in 32 VGPRs, per-row scale,
// exact int32 accumulate) -> no cross-lane reduction. h (int8) broadcast
// from LDS via 8x ds_read_b128 (same-address across lanes = conflict-free).
// Gate exchange: quad_perm DPP broadcasts (VALU-speed) -- the only LDS
// round-trip per step is the h publish itself. One lgkm-only barrier/step.
// ---------------------------------------------------------------------------
__global__ __launch_bounds__(512)
void scan_kernel(const __half* __restrict__ gx, const float* __restrict__ Whh2,
                 const float* __restrict__ h20, const float* __restrict__ c20,
                 float* __restrict__ hist)
{
  __shared__ __align__(16) signed char hq[2][FDIM];   // int8 h, double-buffered

  const int tid  = threadIdx.x;
  const int lane = tid & 63;
  const int wave = tid >> 6;        // 0..7
  const int g    = lane & 3;        // gate {i,f,g,o} within the quad
  const int ul   = lane >> 2;       // 0..15
  const int u    = 16 * wave + ul;  // 0..127
  const int row  = g * FDIM + u;    // unique W_hh2 row per lane (512 total)

  // ---- init: quantize own W_hh2 row to int8 with per-row scale ----
  const float* wr = Whh2 + (size_t)row * FDIM;
  float m = 1e-20f;
#pragma unroll
  for (int k = 0; k < FDIM; k += 4) {
    const float4 v = *(const float4*)(wr + k);
    m = fmaxf(m, fmaxf(fmaxf(fabsf(v.x), fabsf(v.y)),
                       fmaxf(fabsf(v.z), fabsf(v.w))));
  }
  const float inv = 127.f / m;
  const float dq  = m * (1.f / 16129.f);    // m/127 * 1/127
  int wq[32];
#pragma unroll
  for (int d = 0; d < 32; ++d) {
    const float4 v = *(const float4*)(wr + 4 * d);
    int b0 = (int)rintf(v.x * inv), b1 = (int)rintf(v.y * inv);
    int b2 = (int)rintf(v.z * inv), b3 = (int)rintf(v.w * inv);
    b0 = b0 < -127 ? -127 : (b0 > 127 ? 127 : b0);
    b1 = b1 < -127 ? -127 : (b1 > 127 ? 127 : b1);
    b2 = b2 < -127 ? -127 : (b2 > 127 ? 127 : b2);
    b3 = b3 < -127 ? -127 : (b3 > 127 ? 127 : b3);
    wq[d] = (b0 & 255) | ((b1 & 255) << 8) | ((b2 & 255) << 16) | ((b3 & 255) << 24);
  }

  // lane-constant activation selectors: gate 2 uses tanh = 2*sigmoid(2x)-1
  const bool isg  = (g == 2);
  const float selm = isg ? 2.f : 1.f;
  const float selA = isg ? 2.f : 1.f;
  const float selB = isg ? -1.f : 0.f;

  float c = c20[u];                 // redundant across the 4 quad lanes
  if (tid < FDIM) {
    const float hv = fminf(fmaxf(h20[tid], -1.f), 1.f);
    hq[0][tid] = (signed char)(int)rintf(127.f * hv);
  }

  const char* gxb = (const char*)gx;        // step stride: 128 units * 8 B
  const int goff  = u * 8 + g * 2;          // this lane's gate value (f16)
  unsigned short gpf[8];
#pragma unroll
  for (int s = 0; s < 8; ++s)
    gpf[s] = *(const unsigned short*)(gxb + (size_t)s * 1024 + goff);

  __syncthreads();

  for (int t = 0; t < T_LEN; t += 8) {
#pragma unroll
    for (int s = 0; s < 8; ++s) {
      const int tt = t + s;
      const signed char* hrow = hq[tt & 1];

      // 32x sdot4 in 4 independent chains; h broadcast (same addr all lanes)
      int acc0 = 0, acc1 = 0, acc2 = 0, acc3 = 0;
#pragma unroll
      for (int r = 0; r < 8; ++r) {
        const iv4 hv = *(const iv4*)(hrow + 16 * r);
        acc0 = __builtin_amdgcn_sdot4(wq[4 * r + 0], hv.x, acc0, false);
        acc1 = __builtin_amdgcn_sdot4(wq[4 * r + 1], hv.y, acc1, false);
        acc2 = __builtin_amdgcn_sdot4(wq[4 * r + 2], hv.z, acc2, false);
        acc3 = __builtin_amdgcn_sdot4(wq[4 * r + 3], hv.w, acc3, false);
      }
      const int iacc = (acc0 + acc1) + (acc2 + acc3);

      __half_raw hrw; hrw.x = gpf[s];
      const float gxf = __half2float(*(__half*)&hrw);
      gpf[s] = *(const unsigned short*)(
          gxb + (size_t)((tt + 8) & (T_LEN - 1)) * 1024 + goff);

      // pre-activation and this lane's gate activation (1 exp2 + 1 rcp)
      const float pre = fmaf((float)iacc, dq, gxf);
      const float e   = __builtin_amdgcn_exp2f(-LOG2E * (pre * selm));
      const float act = fmaf(frcp(1.f + e), selA, selB);
      // quad now holds: lane g=0: sig(i), g=1: sig(f), g=2: tanh(g), g=3: sig(o)

      // quad-DPP gate exchange (no LDS, no barrier)
      const float tg = qbcast<2>(act);      // tanh(g) to all quad lanes
      const float tp = act * tg;            // lane 0: sig(i)*tanh(g)
      const float p  = qbcast<0>(tp);       // product to all quad lanes
      const float f  = qbcast<1>(act);      // sig(f) to all quad lanes
      c = fmaf(f, c, p);
      const float tc = fmaf(frcp(1.f + __builtin_amdgcn_exp2f(-2.f * LOG2E * c)),
                            2.f, -1.f);     // tanh(c)
      const float o  = qbcast<3>(act);      // sig(o) to all quad lanes
      const float h  = o * tc;

      if (g == 0) {
        hq[(tt + 1) & 1][u] = (signed char)(int)rintf(127.f * h);
        hist[(size_t)tt * FDIM + u] = h;     // fire-and-forget
      }
      LDS_BARRIER();
    }
  }
}

// ---------------------------------------------------------------------------
// Phase C: out[t] = 2*sigmoid(W_fc @ h2[t] + b_fc), in place on d_out.
// ---------------------------------------------------------------------------
__global__ __launch_bounds__(512, 2)
void fc_kernel(const float* __restrict__ Wfc, const float* __restrict__ bfc,
               float* __restrict__ io)
{
  __shared__ float hs[64 * FDIM];
  const int tid  = threadIdx.x;
  const int lane = tid & 63;
  const int wave = tid >> 6;
  const int q    = lane & 15;
  const int gl   = lane >> 4;
  const int g    = wave * 4 + gl;           // 0..31

  float w[4][8];
#pragma unroll
  for (int r = 0; r < 4; ++r)
#pragma unroll
    for (int k = 0; k < 8; ++k)
      w[r][k] = Wfc[(4 * g + r) * FDIM + q * 8 + k];
  const float4 bias = ((const float4*)bfc)[g];

  const int t0 = blockIdx.x * 64;
  float4* iog = (float4*)(io + (size_t)t0 * FDIM);
  float4* hs4 = (float4*)hs;
#pragma unroll
  for (int i = 0; i < 4; ++i) hs4[tid + i * 512] = iog[tid + i * 512];
  __syncthreads();          // all reads of this block's rows done before writes

  for (int tt = 0; tt < 64; ++tt) {
    float hv[8];
    const float4* hv4 = (const float4*)(hs + tt * FDIM + q * 8);
    *(float4*)&hv[0] = hv4[0];
    *(float4*)&hv[4] = hv4[1];
    float acc[4];
#pragma unroll
    for (int r = 0; r < 4; ++r) {
      float a = 0.f;
#pragma unroll
      for (int k = 0; k < 8; ++k) a = fmaf(w[r][k], hv[k], a);
      acc[r] = red16(a);
    }
    if (q == 15) {
      float4 o;
      o.x = 2.f * sigmoid_f(acc[0] + bias.x);
      o.y = 2.f * sigmoid_f(acc[1] + bias.y);
      o.z = 2.f * sigmoid_f(acc[2] + bias.z);
      o.w = 2.f * sigmoid_f(acc[3] + bias.w);
      *(float4*)(io + (size_t)(t0 + tt) * FDIM + 4 * g) = o;
    }
  }
}

// ---------------------------------------------------------------------------
extern "C" void kernel_launch(void* const* d_in, const int* in_sizes, int n_in,
                              void* d_out, int out_size, void* d_ws, size_t ws_size,
                              hipStream_t stream) {
  const float* x    = (const float*)d_in[0];
  // d_in[1..2]: h1_0/c1_0  -- layer-1 LSTM never affects the output: skipped.
  const float* h20  = (const float*)d_in[3];
  const float* c20  = (const float*)d_in[4];
  // d_in[5..8]: W_ih1/W_hh1/b_ih1/b_hh1 -- dead.
  const float* Wih2 = (const float*)d_in[9];
  const float* Whh2 = (const float*)d_in[10];
  const float* bih2 = (const float*)d_in[11];
  const float* bhh2 = (const float*)d_in[12];
  const float* Wfc  = (const float*)d_in[13];
  const float* bfc  = (const float*)d_in[14];

  float*  out = (float*)d_out;              // [T,128]: h2 history, then final out
  __half* gx  = (__half*)d_ws;              // [T][128][4] f16 gate quads (67 MB)

  gx_kernel<<<T_LEN / 64, 512, 0, stream>>>(x, Wih2, bih2, bhh2, gx);
  scan_kernel<<<1, 512, 0, stream>>>(gx, Whh2, h20, c20, out);
  fc_kernel<<<T_LEN / 64, 512, 0, stream>>>(Wfc, bfc, out);
}